// Round 2
// baseline (811.964 us; speedup 1.0000x reference)
//
#include <hip/hip_runtime.h>
#include <hip/hip_bf16.h>
#include <cmath>

#define NROWS 8192
#define DIM   128
#define KDIM  8192
#define BM    64
#define BN    128
#define SPLITK 8
#define KCHUNK (KDIM / SPLITK)    // 1024
#define HSTEPS (KCHUNK / 32)      // 32 half-steps of k=32 each
#define MTILES (NROWS / BM)       // 128
#define LDSTRIDE 80               // proj kernel only

typedef __bf16 bf16_t;
typedef __bf16 bf16x8 __attribute__((ext_vector_type(8)));
typedef float  f32x4  __attribute__((ext_vector_type(4)));

// ------------- theta: transpose to [k][o][i], scale by c_k, bf16 ------------
__global__ void k_theta(const float* __restrict__ th, bf16_t* __restrict__ out,
                        float c0, float c1, float c2, float c3, float c4) {
    int idx = blockIdx.x * 256 + threadIdx.x;          // 81920 total
    int k = idx >> 14;
    int o = (idx >> 7) & 127;
    int i = idx & 127;
    float c = (k == 0) ? c0 : (k == 1) ? c1 : (k == 2) ? c2 : (k == 3) ? c3 : c4;
    out[idx] = (bf16_t)(c * th[(k << 14) + (i << 7) + o]);
}

// --------- GEMM: partial[s] = L[:, chunk_s] @ T_chunk ----------------------
// Barrier-free, LDS-free register-streaming GEMM. Each wave owns a 32x64
// output quadrant; A/B MFMA fragments are loaded straight from global
// (64B-coalesced per 16-lane group; B is L2-resident, 512 KB per chunk),
// 3-deep register rotation hides L2/L3 latency, 12 waves/CU add TLP.
// CVT=1: A is fp32 (first GEMM); convert in-register and have waves 0-1
// write the bf16 row-major copy to Lbf for GEMMs 2-4.
struct Frag { bf16x8 a0, a1, b0, b1, b2, b3; };

template <int CVT>
__global__ __launch_bounds__(256, 3)
void k_gemm(const void* __restrict__ Ap, const bf16_t* __restrict__ Bt,
            float* __restrict__ partial, bf16_t* __restrict__ Lbf_out) {
    const int t     = threadIdx.x;
    const int s     = blockIdx.x & (SPLITK - 1);   // s -> XCD: B chunk pinned per-XCD L2
    const int mTile = blockIdx.x >> 3;
    const int mb    = mTile * BM;
    const int wave = t >> 6, lane = t & 63;
    const int wM = (wave & 1) * 32;
    const int wN = (wave >> 1) * 64;
    const int lm = lane & 15, lk = lane >> 4;
    const int kbase = s * KCHUNK + lk * 8;         // this lane's k offset
    const int rowA  = mb + wM + lm;

    const bf16_t* bP = Bt + (size_t)(wN + lm) * KDIM + kbase;
    const bf16_t* aP = (const bf16_t*)Ap + (size_t)rowA * KDIM + kbase;
    const float*  aF = (const float*)Ap + (size_t)rowA * KDIM + kbase;
    bf16_t*       wP = CVT ? (Lbf_out + (size_t)rowA * KDIM + kbase) : nullptr;

    f32x4 acc[2][4];
#pragma unroll
    for (int a = 0; a < 2; ++a)
#pragma unroll
        for (int b = 0; b < 4; ++b) acc[a][b] = (f32x4)0.0f;

    auto loadF = [&](int h, Frag& f) {
        const int off = h * 32;                    // elements (bf16 or fp32)
        if (CVT) {
            float4 x0 = *(const float4*)(aF + off);
            float4 x1 = *(const float4*)(aF + off + 4);
            float4 y0 = *(const float4*)(aF + (size_t)16 * KDIM + off);
            float4 y1 = *(const float4*)(aF + (size_t)16 * KDIM + off + 4);
            bf16x8 va, vb;
            va[0] = (bf16_t)x0.x; va[1] = (bf16_t)x0.y; va[2] = (bf16_t)x0.z; va[3] = (bf16_t)x0.w;
            va[4] = (bf16_t)x1.x; va[5] = (bf16_t)x1.y; va[6] = (bf16_t)x1.z; va[7] = (bf16_t)x1.w;
            vb[0] = (bf16_t)y0.x; vb[1] = (bf16_t)y0.y; vb[2] = (bf16_t)y0.z; vb[3] = (bf16_t)y0.w;
            vb[4] = (bf16_t)y1.x; vb[5] = (bf16_t)y1.y; vb[6] = (bf16_t)y1.z; vb[7] = (bf16_t)y1.w;
            f.a0 = va; f.a1 = vb;
            if (wave < 2) {                        // each A element stored once
                *(bf16x8*)(wP + off) = va;
                *(bf16x8*)(wP + (size_t)16 * KDIM + off) = vb;
            }
        } else {
            f.a0 = *(const bf16x8*)(aP + off);
            f.a1 = *(const bf16x8*)(aP + (size_t)16 * KDIM + off);
        }
        f.b0 = *(const bf16x8*)(bP + off);
        f.b1 = *(const bf16x8*)(bP + (size_t)16 * KDIM + off);
        f.b2 = *(const bf16x8*)(bP + (size_t)32 * KDIM + off);
        f.b3 = *(const bf16x8*)(bP + (size_t)48 * KDIM + off);
    };
    auto mma = [&](const Frag& f) {
        acc[0][0] = __builtin_amdgcn_mfma_f32_16x16x32_bf16(f.a0, f.b0, acc[0][0], 0, 0, 0);
        acc[0][1] = __builtin_amdgcn_mfma_f32_16x16x32_bf16(f.a0, f.b1, acc[0][1], 0, 0, 0);
        acc[0][2] = __builtin_amdgcn_mfma_f32_16x16x32_bf16(f.a0, f.b2, acc[0][2], 0, 0, 0);
        acc[0][3] = __builtin_amdgcn_mfma_f32_16x16x32_bf16(f.a0, f.b3, acc[0][3], 0, 0, 0);
        acc[1][0] = __builtin_amdgcn_mfma_f32_16x16x32_bf16(f.a1, f.b0, acc[1][0], 0, 0, 0);
        acc[1][1] = __builtin_amdgcn_mfma_f32_16x16x32_bf16(f.a1, f.b1, acc[1][1], 0, 0, 0);
        acc[1][2] = __builtin_amdgcn_mfma_f32_16x16x32_bf16(f.a1, f.b2, acc[1][2], 0, 0, 0);
        acc[1][3] = __builtin_amdgcn_mfma_f32_16x16x32_bf16(f.a1, f.b3, acc[1][3], 0, 0, 0);
    };

    Frag f0, f1, f2;
    loadF(0, f0); loadF(1, f1);
    // (HSTEPS-2) divisible by 3: 32-2 = 30 -> 10 rotations.
#pragma unroll
    for (int it = 0; it < (HSTEPS - 2) / 3; ++it) {
        const int h = 2 + it * 3;
        loadF(h,     f2); mma(f0);
        loadF(h + 1, f0); mma(f1);
        loadF(h + 2, f1); mma(f2);
    }
    mma(f0); mma(f1);

    float* pOut = partial + (size_t)s * NROWS * DIM;
#pragma unroll
    for (int tm = 0; tm < 2; ++tm)
#pragma unroll
        for (int tn = 0; tn < 4; ++tn)
#pragma unroll
            for (int r = 0; r < 4; ++r) {
                const int row = mb + wM + tm * 16 + lk * 4 + r;
                const int col = wN + tn * 16 + lm;
                pOut[(size_t)row * DIM + col] = acc[tm][tn][r];
            }
}

// ---- combine: y = sum(partials) [or x]; recurrence; emit fp32/Tbf/Bt -------
// MODE 0: y = src (fp32 x).  MODE 1: y = sum_s partial.  MODE 2: 2*sum - prev.
// bt output is the plain transpose [feat][node] consumed by the gemm B-path.
template <int MODE>
__global__ void k_combine(const float* __restrict__ src, const float* __restrict__ prev,
                          float* __restrict__ f32dst, bf16_t* __restrict__ tbf,
                          bf16_t* __restrict__ bt) {
    __shared__ bf16_t tl[128 * 24];      // [feat][16 node + pad]
    const size_t S = (size_t)NROWS * DIM;
    const int t  = threadIdx.x;
    const int n0 = blockIdx.x * 16;
    const int nl = t >> 4;               // 0..15 node within tile
    const int dp = (t & 15) * 8;         // 0..120 feature offset
    const int n  = n0 + nl;

    float y[8];
    if (MODE == 0) {
        float4 a = *(const float4*)(src + (size_t)n * DIM + dp);
        float4 b = *(const float4*)(src + (size_t)n * DIM + dp + 4);
        y[0] = a.x; y[1] = a.y; y[2] = a.z; y[3] = a.w;
        y[4] = b.x; y[5] = b.y; y[6] = b.z; y[7] = b.w;
    } else {
#pragma unroll
        for (int j = 0; j < 8; ++j) y[j] = 0.0f;
#pragma unroll
        for (int ss = 0; ss < SPLITK; ++ss) {
            const float* p = src + (size_t)ss * S + (size_t)n * DIM + dp;
            float4 a = *(const float4*)p;
            float4 b = *(const float4*)(p + 4);
            y[0] += a.x; y[1] += a.y; y[2] += a.z; y[3] += a.w;
            y[4] += b.x; y[5] += b.y; y[6] += b.z; y[7] += b.w;
        }
        if (MODE == 2) {
            float4 a = *(const float4*)(prev + (size_t)n * DIM + dp);
            float4 b = *(const float4*)(prev + (size_t)n * DIM + dp + 4);
            y[0] = 2.0f * y[0] - a.x; y[1] = 2.0f * y[1] - a.y;
            y[2] = 2.0f * y[2] - a.z; y[3] = 2.0f * y[3] - a.w;
            y[4] = 2.0f * y[4] - b.x; y[5] = 2.0f * y[5] - b.y;
            y[6] = 2.0f * y[6] - b.z; y[7] = 2.0f * y[7] - b.w;
        }
    }
    if (f32dst) {
        float4 a, b;
        a.x = y[0]; a.y = y[1]; a.z = y[2]; a.w = y[3];
        b.x = y[4]; b.y = y[5]; b.z = y[6]; b.w = y[7];
        *(float4*)(f32dst + (size_t)n * DIM + dp) = a;
        *(float4*)(f32dst + (size_t)n * DIM + dp + 4) = b;
    }
    bf16x8 v;
#pragma unroll
    for (int j = 0; j < 8; ++j) v[j] = (bf16_t)y[j];
    *(bf16x8*)(tbf + (size_t)n * DIM + dp) = v;
    if (bt) {
#pragma unroll
        for (int j = 0; j < 8; ++j) tl[(dp + j) * 24 + nl] = v[j];
        __syncthreads();
        const int d = t >> 1;                 // feat 0..127
        const int h = (t & 1) * 8;            // node sub-offset 0/8
        bf16x8 w = *(const bf16x8*)(&tl[d * 24 + h]);
        *(bf16x8*)(bt + (size_t)d * NROWS + n0 + h) = w;
    }
}

// ------- projection: out = sum_seg Tbf[seg] @ thT[seg]^T (c_k pre-folded) ----
__global__ __launch_bounds__(256, 2)
void k_proj(const bf16_t* __restrict__ T, const bf16_t* __restrict__ W,
            float* __restrict__ out) {
    __shared__ __align__(16) bf16_t As[64 * LDSTRIDE];
    __shared__ __align__(16) bf16_t Bs[128 * LDSTRIDE];

    const int t  = threadIdx.x;
    const int mb = blockIdx.x * 64;
    const int wave = t >> 6, lane = t & 63;
    const int wM = (wave & 1) * 32;
    const int wN = (wave >> 1) * 64;
    const int lm = lane & 15, lk = lane >> 4;
    const int arow = t >> 3;
    const int asc  = t & 7;
    const size_t S = (size_t)NROWS * DIM;

    f32x4 acc[2][4];
#pragma unroll
    for (int a = 0; a < 2; ++a)
#pragma unroll
        for (int b = 0; b < 4; ++b) acc[a][b] = (f32x4)0.0f;

    bf16x8 aR[2], bR[4];

    auto loadT = [&](int it) {
        const int seg = it >> 1;
        const int h   = (it & 1) * 64;
#pragma unroll
        for (int rep = 0; rep < 2; ++rep) {
            const int r = rep * 32 + arow;
            aR[rep] = *(const bf16x8*)(T + (size_t)seg * S +
                        (size_t)(mb + r) * DIM + h + asc * 8);
        }
#pragma unroll
        for (int rep = 0; rep < 4; ++rep) {
            const int o = rep * 32 + arow;
            bR[rep] = *(const bf16x8*)(W + seg * 16384 + o * 128 + h + asc * 8);
        }
    };
    auto storeT = [&]() {
#pragma unroll
        for (int rep = 0; rep < 2; ++rep) {
            const int r = rep * 32 + arow;
            *(bf16x8*)(&As[r * LDSTRIDE + asc * 8]) = aR[rep];
        }
#pragma unroll
        for (int rep = 0; rep < 4; ++rep) {
            const int o = rep * 32 + arow;
            *(bf16x8*)(&Bs[o * LDSTRIDE + asc * 8]) = bR[rep];
        }
    };

    loadT(0);
    for (int it = 0; it < 10; ++it) {
        __syncthreads();
        storeT();
        __syncthreads();
        if (it + 1 < 10) loadT(it + 1);
#pragma unroll
        for (int ko = 0; ko < 2; ++ko) {
            bf16x8 af[2], bfr[4];
#pragma unroll
            for (int tm = 0; tm < 2; ++tm)
                af[tm] = *(const bf16x8*)(&As[(wM + tm * 16 + lm) * LDSTRIDE +
                                              (ko * 4 + lk) * 8]);
#pragma unroll
            for (int tn = 0; tn < 4; ++tn)
                bfr[tn] = *(const bf16x8*)(&Bs[(wN + tn * 16 + lm) * LDSTRIDE +
                                               (ko * 4 + lk) * 8]);
#pragma unroll
            for (int tm = 0; tm < 2; ++tm)
#pragma unroll
                for (int tn = 0; tn < 4; ++tn)
                    acc[tm][tn] = __builtin_amdgcn_mfma_f32_16x16x32_bf16(
                        af[tm], bfr[tn], acc[tm][tn], 0, 0, 0);
        }
    }
#pragma unroll
    for (int tm = 0; tm < 2; ++tm)
#pragma unroll
        for (int tn = 0; tn < 4; ++tn)
#pragma unroll
            for (int r = 0; r < 4; ++r) {
                const int row = mb + wM + tm * 16 + lk * 4 + r;
                const int col = wN + tn * 16 + lm;
                out[(size_t)row * DIM + col] = acc[tm][tn][r];
            }
}

extern "C" void kernel_launch(void* const* d_in, const int* in_sizes, int n_in,
                              void* d_out, int out_size, void* d_ws, size_t ws_size,
                              hipStream_t stream) {
    const float* x  = nullptr;
    const float* L  = nullptr;
    const float* th = nullptr;
    for (int i = 0; i < n_in; ++i) {
        if (in_sizes[i] == NROWS * KDIM)       L  = (const float*)d_in[i];
        else if (in_sizes[i] == NROWS * DIM)   x  = (const float*)d_in[i];
        else if (in_sizes[i] == 5 * DIM * DIM) th = (const float*)d_in[i];
    }
    float* out = (float*)d_out;

    const size_t S = (size_t)NROWS * DIM;          // 1048576 elems
    char* ws = (char*)d_ws;
    size_t off = 0;
    auto alloc = [&](size_t bytes) {
        void* p = ws + off;
        off = (off + bytes + 255) & ~(size_t)255;
        return p;
    };
    bf16_t* Tbf     = (bf16_t*)alloc(5 * S * 2);        // [5][node][feat]
    bf16_t* Bt      = (bf16_t*)alloc(5 * S * 2);        // [5][feat][node]
    float*  Tf32    = (float*)alloc(2 * S * 4);         // fp32 recurrence state
    bf16_t* thT     = (bf16_t*)alloc(5 * 128 * 128 * 2);
    float*  partial = (float*)alloc((size_t)SPLITK * S * 4);   // 32 MB
    bf16_t* Lbf     = (bf16_t*)alloc((size_t)NROWS * KDIM * 2); // row-major bf16
    if (off > ws_size) return;

    float c[5];
    for (int k = 0; k < 5; ++k)
        c[k] = (float)((2.0 / 5.0) * exp(-0.5 * cos(M_PI * (k + 0.5) / 5.0)));

    dim3 blk(256);
    k_theta<<<320, blk, 0, stream>>>(th, thT, c[0], c[1], c[2], c[3], c[4]);
    k_combine<0><<<512, blk, 0, stream>>>(x, nullptr, nullptr, Tbf, Bt);

    for (int j = 1; j <= 4; ++j) {
        const bf16_t* Bj = Bt + (size_t)(j - 1) * S;
        if (j == 1)
            k_gemm<1><<<MTILES * SPLITK, blk, 0, stream>>>(L, Bj, partial, Lbf);
        else
            k_gemm<0><<<MTILES * SPLITK, blk, 0, stream>>>(Lbf, Bj, partial, nullptr);
        bf16_t* tbf = Tbf + (size_t)j * S;
        bf16_t* bt  = (j < 4) ? Bt + (size_t)j * S : nullptr;
        if (j == 1)
            k_combine<1><<<512, blk, 0, stream>>>(partial, nullptr, Tf32 + S, tbf, bt);
        else if (j == 2)
            k_combine<2><<<512, blk, 0, stream>>>(partial, x, Tf32, tbf, bt);
        else if (j == 3)
            k_combine<2><<<512, blk, 0, stream>>>(partial, Tf32 + S, Tf32 + S, tbf, bt);
        else
            k_combine<2><<<512, blk, 0, stream>>>(partial, Tf32, nullptr, tbf, nullptr);
    }
    k_proj<<<128, blk, 0, stream>>>(Tbf, thT, out);
}

// Round 3
// 552.081 us; speedup vs baseline: 1.4707x; 1.4707x over previous
//
#include <hip/hip_runtime.h>
#include <hip/hip_bf16.h>
#include <cmath>

#define NROWS 8192
#define DIM   128
#define KDIM  8192
#define BM    128
#define BN    128
#define BK    32
#define SPLITK 8
#define KCHUNK (KDIM / SPLITK)    // 1024
#define GITERS (KCHUNK / BK)      // 32
#define MTILES (NROWS / BM)       // 64
#define KB32   (KDIM / 32)        // 256 A-image k-blocks
#define NB32   (NROWS / 32)       // 256 B-image node-blocks
#define NBUF   4
#define LDSTRIDE 80               // proj kernel only

typedef __bf16 bf16_t;
typedef __bf16 bf16x8 __attribute__((ext_vector_type(8)));
typedef float  f32x4  __attribute__((ext_vector_type(4)));

// DMA-image layout (both operands): the matrix is tiled into units of
// 16 rows x 32 k (1 KB). Unit (rg, kblk) holds lane-ordered 16B packets:
//   lane = p*16 + lrow  <->  (row = rg*16 + lrow, k = kblk*32 + p*8)
//   img16[(rg * KB32 + kblk) * 64 + lane]
// A wave-level global_load_lds of 1 KB lands the unit in LDS as
// [pos p][row lrow] 16B packets; MFMA frag reads at lk*128 + lm*8 elems
// are then bank-uniform (lanes differ by lm*16B -> 2-way, free).

__device__ __forceinline__ void async16(const void* g, void* l) {
    __builtin_amdgcn_global_load_lds(
        (const __attribute__((address_space(1))) unsigned int*)g,
        (__attribute__((address_space(3))) unsigned int*)l, 16, 0, 0);
}

// ------------- theta: transpose to [k][o][i], scale by c_k, bf16 ------------
__global__ void k_theta(const float* __restrict__ th, bf16_t* __restrict__ out,
                        float c0, float c1, float c2, float c3, float c4) {
    int idx = blockIdx.x * 256 + threadIdx.x;          // 81920 total
    int k = idx >> 14;
    int o = (idx >> 7) & 127;
    int i = idx & 127;
    float c = (k == 0) ? c0 : (k == 1) ? c1 : (k == 2) ? c2 : (k == 3) ? c3 : c4;
    out[idx] = (bf16_t)(c * th[(k << 14) + (i << 7) + o]);
}

// ---- convert: fp32 L (row-major) -> bf16 Lbf in DMA-image layout -----------
// Each wave emits one 1 KB image unit per step; global reads consume full
// 128B lines (4 p-lanes cover one row's 32 floats); writes are contiguous.
__global__ __launch_bounds__(256)
void k_convert(const float* __restrict__ L, bf16_t* __restrict__ img) {
    const int lane = threadIdx.x & 63;
    const int p = lane >> 4, lrow = lane & 15;
    const int wid = blockIdx.x * 4 + (threadIdx.x >> 6);
    const int nW = gridDim.x * 4;
    const int TOT = (NROWS / 16) * KB32;       // 131072 units
    for (int u = wid; u < TOT; u += nW) {
        const int rg = u >> 8;                  // KB32 = 256
        const int kblk = u & (KB32 - 1);
        const float* src = L + (size_t)(rg * 16 + lrow) * KDIM + kblk * 32 + p * 8;
        float4 a = *(const float4*)src;
        float4 b = *(const float4*)(src + 4);
        bf16x8 v;
        v[0] = (bf16_t)a.x; v[1] = (bf16_t)a.y; v[2] = (bf16_t)a.z; v[3] = (bf16_t)a.w;
        v[4] = (bf16_t)b.x; v[5] = (bf16_t)b.y; v[6] = (bf16_t)b.z; v[7] = (bf16_t)b.w;
        *(bf16x8*)(img + (((size_t)rg * KB32 + kblk) * 64 + lane) * 8) = v;
    }
}

// --------- GEMM: partial[s] = L[:, chunk_s] @ T_chunk ----------------------
// 512 threads (8 waves, wave tile 32x64), BM=BN=128, BK=32.
// 4-buffer global_load_lds pipeline, counted vmcnt: 2 loads/wave/tile,
// 3 tiles in flight -> steady-state s_waitcnt vmcnt(6). 64 KB LDS ->
// 2 blocks/CU = 16 waves/CU.
__global__ __launch_bounds__(512, 4)
void k_gemm(const bf16_t* __restrict__ A, const bf16_t* __restrict__ Bt,
            float* __restrict__ partial) {
    __shared__ __align__(16) bf16_t As[NBUF][BM * BK];   // 4 x 8 KB
    __shared__ __align__(16) bf16_t Bs[NBUF][BN * BK];   // 4 x 8 KB

    const int t     = threadIdx.x;
    const int s     = blockIdx.x & (SPLITK - 1);  // s -> XCD: B chunk per-XCD L2
    const int mTile = blockIdx.x >> 3;
    const int mb    = mTile * BM;
    const int wave = t >> 6, lane = t & 63;
    const int wM = (wave & 3) * 32;
    const int wN = (wave >> 2) * 64;
    const int lm = lane & 15, lk = lane >> 4;
    const int kb0 = s * (KCHUNK / 32);            // first 32-k image block

    f32x4 acc[2][4];
#pragma unroll
    for (int a = 0; a < 2; ++a)
#pragma unroll
        for (int b = 0; b < 4; ++b) acc[a][b] = (f32x4)0.0f;

    // 2 global_load_lds per wave per tile: wave w stages A row-group w and
    // B feat-group w (1 KB each, lane-contiguous).
    auto stage = [&](int kk, int buf) {
        const int kblk = kb0 + kk;
        async16(A + (((size_t)((mb >> 4) + wave) * KB32 + kblk) * 64 + lane) * 8,
                &As[buf][wave * 512]);
        async16(Bt + (((size_t)wave * NB32 + kblk) * 64 + lane) * 8,
                &Bs[buf][wave * 512]);
    };

    auto compute = [&](int buf) {
        bf16x8 af[2], bfr[4];
#pragma unroll
        for (int tm = 0; tm < 2; ++tm)
            af[tm] = *(const bf16x8*)(&As[buf][((wM >> 4) + tm) * 512 + lk * 128 + lm * 8]);
#pragma unroll
        for (int tn = 0; tn < 4; ++tn)
            bfr[tn] = *(const bf16x8*)(&Bs[buf][((wN >> 4) + tn) * 512 + lk * 128 + lm * 8]);
        __builtin_amdgcn_s_setprio(1);
#pragma unroll
        for (int tm = 0; tm < 2; ++tm)
#pragma unroll
            for (int tn = 0; tn < 4; ++tn)
                acc[tm][tn] = __builtin_amdgcn_mfma_f32_16x16x32_bf16(
                    af[tm], bfr[tn], acc[tm][tn], 0, 0, 0);
        __builtin_amdgcn_s_setprio(0);
    };

    // Prologue: fill all 4 buffers (8 loads/wave in flight).
    stage(0, 0); stage(1, 1); stage(2, 2); stage(3, 3);

    for (int kk = 0; kk < GITERS - 3; ++kk) {
        const int buf = kk & 3;
        // Own tile-kk loads done; newest 6 (tiles kk+1..kk+3) may remain.
        asm volatile("s_waitcnt vmcnt(6)" ::: "memory");
        __builtin_amdgcn_s_barrier();              // all waves: tile kk in LDS
        __builtin_amdgcn_sched_barrier(0);
        compute(buf);
        __builtin_amdgcn_sched_barrier(0);
        __builtin_amdgcn_s_barrier();              // all waves done reading buf
        if (kk + 4 < GITERS) stage(kk + 4, buf);   // refill freed buffer
    }
    // Peeled tail: GITERS-3 (2 tiles in flight), GITERS-2 (1), GITERS-1 (0).
    asm volatile("s_waitcnt vmcnt(4)" ::: "memory");
    __builtin_amdgcn_s_barrier();
    __builtin_amdgcn_sched_barrier(0);
    compute((GITERS - 3) & 3);
    __builtin_amdgcn_sched_barrier(0);
    __builtin_amdgcn_s_barrier();
    asm volatile("s_waitcnt vmcnt(2)" ::: "memory");
    __builtin_amdgcn_s_barrier();
    __builtin_amdgcn_sched_barrier(0);
    compute((GITERS - 2) & 3);
    __builtin_amdgcn_sched_barrier(0);
    __builtin_amdgcn_s_barrier();
    asm volatile("s_waitcnt vmcnt(0)" ::: "memory");
    __builtin_amdgcn_s_barrier();
    __builtin_amdgcn_sched_barrier(0);
    compute((GITERS - 1) & 3);

    float* pOut = partial + (size_t)s * NROWS * DIM;
#pragma unroll
    for (int tm = 0; tm < 2; ++tm)
#pragma unroll
        for (int tn = 0; tn < 4; ++tn)
#pragma unroll
            for (int r = 0; r < 4; ++r) {
                const int row = mb + wM + tm * 16 + lk * 4 + r;
                const int col = wN + tn * 16 + lm;
                pOut[(size_t)row * DIM + col] = acc[tm][tn][r];
            }
}

// ---- combine: y = sum(partials) [or x]; recurrence; emit fp32/Tbf/Bt -------
// MODE 0: y = src (fp32 x).  MODE 1: y = sum_s partial.  MODE 2: 2*sum - prev.
// bt output is written in the gemm's DMA-image layout over [feat][node-k].
template <int MODE>
__global__ void k_combine(const float* __restrict__ src, const float* __restrict__ prev,
                          float* __restrict__ f32dst, bf16_t* __restrict__ tbf,
                          bf16_t* __restrict__ bt) {
    __shared__ bf16_t tl[128 * 24];      // [feat][16 node + pad]
    const size_t S = (size_t)NROWS * DIM;
    const int t  = threadIdx.x;
    const int n0 = blockIdx.x * 16;
    const int nl = t >> 4;               // 0..15 node within tile
    const int dp = (t & 15) * 8;         // 0..120 feature offset
    const int n  = n0 + nl;

    float y[8];
    if (MODE == 0) {
        float4 a = *(const float4*)(src + (size_t)n * DIM + dp);
        float4 b = *(const float4*)(src + (size_t)n * DIM + dp + 4);
        y[0] = a.x; y[1] = a.y; y[2] = a.z; y[3] = a.w;
        y[4] = b.x; y[5] = b.y; y[6] = b.z; y[7] = b.w;
    } else {
#pragma unroll
        for (int j = 0; j < 8; ++j) y[j] = 0.0f;
#pragma unroll
        for (int ss = 0; ss < SPLITK; ++ss) {
            const float* p = src + (size_t)ss * S + (size_t)n * DIM + dp;
            float4 a = *(const float4*)p;
            float4 b = *(const float4*)(p + 4);
            y[0] += a.x; y[1] += a.y; y[2] += a.z; y[3] += a.w;
            y[4] += b.x; y[5] += b.y; y[6] += b.z; y[7] += b.w;
        }
        if (MODE == 2) {
            float4 a = *(const float4*)(prev + (size_t)n * DIM + dp);
            float4 b = *(const float4*)(prev + (size_t)n * DIM + dp + 4);
            y[0] = 2.0f * y[0] - a.x; y[1] = 2.0f * y[1] - a.y;
            y[2] = 2.0f * y[2] - a.z; y[3] = 2.0f * y[3] - a.w;
            y[4] = 2.0f * y[4] - b.x; y[5] = 2.0f * y[5] - b.y;
            y[6] = 2.0f * y[6] - b.z; y[7] = 2.0f * y[7] - b.w;
        }
    }
    if (f32dst) {
        float4 a, b;
        a.x = y[0]; a.y = y[1]; a.z = y[2]; a.w = y[3];
        b.x = y[4]; b.y = y[5]; b.z = y[6]; b.w = y[7];
        *(float4*)(f32dst + (size_t)n * DIM + dp) = a;
        *(float4*)(f32dst + (size_t)n * DIM + dp + 4) = b;
    }
    bf16x8 v;
#pragma unroll
    for (int j = 0; j < 8; ++j) v[j] = (bf16_t)y[j];
    *(bf16x8*)(tbf + (size_t)n * DIM + dp) = v;
    if (bt) {
#pragma unroll
        for (int j = 0; j < 8; ++j) tl[(dp + j) * 24 + nl] = v[j];
        __syncthreads();
        const int d = t >> 1;                 // feat 0..127
        const int h = (t & 1) * 8;            // node sub-offset 0/8
        bf16x8 w = *(const bf16x8*)(&tl[d * 24 + h]);
        const int nn = n0 + h;
        const size_t a16 = ((size_t)(d >> 4) * NB32 + (nn >> 5)) * 64 +
                           ((nn >> 3) & 3) * 16 + (d & 15);
        *(bf16x8*)(bt + a16 * 8) = w;
    }
}

// ------- projection: out = sum_seg Tbf[seg] @ thT[seg]^T (c_k pre-folded) ----
__global__ __launch_bounds__(256, 2)
void k_proj(const bf16_t* __restrict__ T, const bf16_t* __restrict__ W,
            float* __restrict__ out) {
    __shared__ __align__(16) bf16_t As[64 * LDSTRIDE];
    __shared__ __align__(16) bf16_t Bs[128 * LDSTRIDE];

    const int t  = threadIdx.x;
    const int mb = blockIdx.x * 64;
    const int wave = t >> 6, lane = t & 63;
    const int wM = (wave & 1) * 32;
    const int wN = (wave >> 1) * 64;
    const int lm = lane & 15, lk = lane >> 4;
    const int arow = t >> 3;
    const int asc  = t & 7;
    const size_t S = (size_t)NROWS * DIM;

    f32x4 acc[2][4];
#pragma unroll
    for (int a = 0; a < 2; ++a)
#pragma unroll
        for (int b = 0; b < 4; ++b) acc[a][b] = (f32x4)0.0f;

    bf16x8 aR[2], bR[4];

    auto loadT = [&](int it) {
        const int seg = it >> 1;
        const int h   = (it & 1) * 64;
#pragma unroll
        for (int rep = 0; rep < 2; ++rep) {
            const int r = rep * 32 + arow;
            aR[rep] = *(const bf16x8*)(T + (size_t)seg * S +
                        (size_t)(mb + r) * DIM + h + asc * 8);
        }
#pragma unroll
        for (int rep = 0; rep < 4; ++rep) {
            const int o = rep * 32 + arow;
            bR[rep] = *(const bf16x8*)(W + seg * 16384 + o * 128 + h + asc * 8);
        }
    };
    auto storeT = [&]() {
#pragma unroll
        for (int rep = 0; rep < 2; ++rep) {
            const int r = rep * 32 + arow;
            *(bf16x8*)(&As[r * LDSTRIDE + asc * 8]) = aR[rep];
        }
#pragma unroll
        for (int rep = 0; rep < 4; ++rep) {
            const int o = rep * 32 + arow;
            *(bf16x8*)(&Bs[o * LDSTRIDE + asc * 8]) = bR[rep];
        }
    };

    loadT(0);
    for (int it = 0; it < 10; ++it) {
        __syncthreads();
        storeT();
        __syncthreads();
        if (it + 1 < 10) loadT(it + 1);
#pragma unroll
        for (int ko = 0; ko < 2; ++ko) {
            bf16x8 af[2], bfr[4];
#pragma unroll
            for (int tm = 0; tm < 2; ++tm)
                af[tm] = *(const bf16x8*)(&As[(wM + tm * 16 + lm) * LDSTRIDE +
                                              (ko * 4 + lk) * 8]);
#pragma unroll
            for (int tn = 0; tn < 4; ++tn)
                bfr[tn] = *(const bf16x8*)(&Bs[(wN + tn * 16 + lm) * LDSTRIDE +
                                               (ko * 4 + lk) * 8]);
#pragma unroll
            for (int tm = 0; tm < 2; ++tm)
#pragma unroll
                for (int tn = 0; tn < 4; ++tn)
                    acc[tm][tn] = __builtin_amdgcn_mfma_f32_16x16x32_bf16(
                        af[tm], bfr[tn], acc[tm][tn], 0, 0, 0);
        }
    }
#pragma unroll
    for (int tm = 0; tm < 2; ++tm)
#pragma unroll
        for (int tn = 0; tn < 4; ++tn)
#pragma unroll
            for (int r = 0; r < 4; ++r) {
                const int row = mb + wM + tm * 16 + lk * 4 + r;
                const int col = wN + tn * 16 + lm;
                out[(size_t)row * DIM + col] = acc[tm][tn][r];
            }
}

extern "C" void kernel_launch(void* const* d_in, const int* in_sizes, int n_in,
                              void* d_out, int out_size, void* d_ws, size_t ws_size,
                              hipStream_t stream) {
    const float* x  = nullptr;
    const float* L  = nullptr;
    const float* th = nullptr;
    for (int i = 0; i < n_in; ++i) {
        if (in_sizes[i] == NROWS * KDIM)       L  = (const float*)d_in[i];
        else if (in_sizes[i] == NROWS * DIM)   x  = (const float*)d_in[i];
        else if (in_sizes[i] == 5 * DIM * DIM) th = (const float*)d_in[i];
    }
    float* out = (float*)d_out;

    const size_t S = (size_t)NROWS * DIM;          // 1048576 elems
    char* ws = (char*)d_ws;
    size_t off = 0;
    auto alloc = [&](size_t bytes) {
        void* p = ws + off;
        off = (off + bytes + 255) & ~(size_t)255;
        return p;
    };
    bf16_t* Tbf     = (bf16_t*)alloc(5 * S * 2);        // [5][node][feat]
    bf16_t* Bt      = (bf16_t*)alloc(5 * S * 2);        // [5] DMA-image
    float*  Tf32    = (float*)alloc(2 * S * 4);         // fp32 recurrence state
    bf16_t* thT     = (bf16_t*)alloc(5 * 128 * 128 * 2);
    float*  partial = (float*)alloc((size_t)SPLITK * S * 4);   // 32 MB
    bf16_t* Lbf     = (bf16_t*)alloc((size_t)NROWS * KDIM * 2); // DMA-image
    if (off > ws_size) return;

    float c[5];
    for (int k = 0; k < 5; ++k)
        c[k] = (float)((2.0 / 5.0) * exp(-0.5 * cos(M_PI * (k + 0.5) / 5.0)));

    dim3 blk(256);
    k_theta<<<320, blk, 0, stream>>>(th, thT, c[0], c[1], c[2], c[3], c[4]);
    k_convert<<<2048, blk, 0, stream>>>(L, Lbf);
    k_combine<0><<<512, blk, 0, stream>>>(x, nullptr, nullptr, Tbf, Bt);

    for (int j = 1; j <= 4; ++j) {
        const bf16_t* Bj = Bt + (size_t)(j - 1) * S;
        k_gemm<<<MTILES * SPLITK, dim3(512), 0, stream>>>(Lbf, Bj, partial);
        bf16_t* tbf = Tbf + (size_t)j * S;
        bf16_t* bt  = (j < 4) ? Bt + (size_t)j * S : nullptr;
        if (j == 1)
            k_combine<1><<<512, blk, 0, stream>>>(partial, nullptr, Tf32 + S, tbf, bt);
        else if (j == 2)
            k_combine<2><<<512, blk, 0, stream>>>(partial, x, Tf32, tbf, bt);
        else if (j == 3)
            k_combine<2><<<512, blk, 0, stream>>>(partial, Tf32 + S, Tf32 + S, tbf, bt);
        else
            k_combine<2><<<512, blk, 0, stream>>>(partial, Tf32, nullptr, tbf, nullptr);
    }
    k_proj<<<128, blk, 0, stream>>>(Tbf, thT, out);
}